// Round 2
// baseline (2794.710 us; speedup 1.0000x reference)
//
#include <hip/hip_runtime.h>

#define NROWS 131072
#define KCODES 1024
#define DDIM 256
#define BN 64
#define NBLK (NROWS / BN)   // 2048
#define RW 8                // rows per wave
#define SC 256              // codes staged per chunk
#define NCH (KCODES / SC)   // 4 chunks
#define STR 20              // LDS row stride in floats (16 data + 4 pad; odd 16B-unit stride)
#define COMMIT 0.25

// Prevent -ffp-contract=fast from fusing x*x into the following add
// (numpy rounds the product array first, then pairwise-sums).
__device__ __forceinline__ float opq(float x) {
    asm volatile("" : "+v"(x));
    return x;
}

// numpy pairwise_sum of squares over 256 contiguous elements:
// split 128+128; each half: 8 accumulators r[j] = x[j]+x[j+8]+... (16 terms in order),
// combined as ((r0+r1)+(r2+r3))+((r4+r5)+(r6+r7)); halves added last.
template <typename LD>
__device__ __forceinline__ float pairwise256_sq(LD ld) {
    float tt[2];
#pragma unroll
    for (int h = 0; h < 2; ++h) {
        float r[8];
#pragma unroll
        for (int j = 0; j < 8; ++j) {
            float e = ld(h * 128 + j);
            float p = e * e;
            p = opq(p);
            r[j] = p;
        }
#pragma unroll
        for (int i = 1; i < 16; ++i) {
#pragma unroll
            for (int j = 0; j < 8; ++j) {
                float e = ld(h * 128 + i * 8 + j);
                float p = e * e;
                p = opq(p);
                r[j] += p;
            }
        }
        tt[h] = ((r[0] + r[1]) + (r[2] + r[3])) + ((r[4] + r[5]) + (r[6] + r[7]));
    }
    return tt[0] + tt[1];
}

__global__ void cnorm_k(const float* __restrict__ emb, float* __restrict__ cn) {
    int code = blockIdx.x * blockDim.x + threadIdx.x;
    if (code >= KCODES) return;
    const float* x = emb + (size_t)code * DDIM;
    cn[code] = pairwise256_sq([&](int i) { return x[i]; });
}

__global__ __launch_bounds__(512, 4) void vq_main(
    const float* __restrict__ z_e, const float* __restrict__ emb,
    const float* __restrict__ cn_g, float* __restrict__ out_zq,
    float* __restrict__ out_idx, double* __restrict__ ws_part) {
    __shared__ float ctb[2][SC * STR];  // 2 x 20480 B, [code][d-block] natural layout
    __shared__ double wsum[8];

    const int tid = threadIdx.x;
    const int lane = tid & 63;
    const int wid = __builtin_amdgcn_readfirstlane(tid >> 6);  // wave id, provably uniform
    const int bid = blockIdx.x;
    const size_t row0 = (size_t)bid * BN + (size_t)wid * RW;  // this wave's first row

    // ---- z_norm for the wave's 8 rows (np pairwise order), lanes 0..7 serial ----
    float zn = 0.0f;
    if (lane < 8) {
        const float* x = z_e + (row0 + lane) * DDIM;
        float tt[2];
#pragma unroll
        for (int h = 0; h < 2; ++h) {
            float r8[8];
            {
                float4 a = *(const float4*)(x + h * 128);
                float4 b = *(const float4*)(x + h * 128 + 4);
                r8[0] = opq(a.x * a.x); r8[1] = opq(a.y * a.y);
                r8[2] = opq(a.z * a.z); r8[3] = opq(a.w * a.w);
                r8[4] = opq(b.x * b.x); r8[5] = opq(b.y * b.y);
                r8[6] = opq(b.z * b.z); r8[7] = opq(b.w * b.w);
            }
#pragma unroll
            for (int i = 1; i < 16; ++i) {
                float4 a = *(const float4*)(x + h * 128 + i * 8);
                float4 b = *(const float4*)(x + h * 128 + i * 8 + 4);
                r8[0] += opq(a.x * a.x); r8[1] += opq(a.y * a.y);
                r8[2] += opq(a.z * a.z); r8[3] += opq(a.w * a.w);
                r8[4] += opq(b.x * b.x); r8[5] += opq(b.y * b.y);
                r8[6] += opq(b.z * b.z); r8[7] += opq(b.w * b.w);
            }
            tt[h] = ((r8[0] + r8[1]) + (r8[2] + r8[3])) + ((r8[4] + r8[5]) + (r8[6] + r8[7]));
        }
        zn = tt[0] + tt[1];
    }
    float znb[8];
#pragma unroll
    for (int r = 0; r < 8; ++r) znb[r] = __shfl(zn, r);

    float mv[8];
    int mk[8];
#pragma unroll
    for (int r = 0; r < 8; ++r) {
        mv[r] = __builtin_inff();
        mk[r] = 0;
    }

    const int cc = tid >> 1;  // staging: code within chunk
    const int hh = tid & 1;   // staging: which 8-float half of the 16-d slab

    for (int ch = 0; ch < NCH; ++ch) {
        const int code0 = ch * SC;
        float acc[8][4];
#pragma unroll
        for (int r = 0; r < 8; ++r)
#pragma unroll
            for (int m = 0; m < 4; ++m) acc[r][m] = 0.0f;

        // prologue: stage d-block 0 into buffer 0
        {
            const float* sp = emb + (size_t)(code0 + cc) * DDIM + hh * 8;
            float4 a = *(const float4*)sp;
            float4 b = *(const float4*)(sp + 4);
            float* dp = &ctb[0][cc * STR + hh * 8];
            *(float4*)dp = a;
            *(float4*)(dp + 4) = b;
        }

        for (int db = 0; db < 16; ++db) {
            __syncthreads();
            // stage next d-block into the other buffer (overlaps with compute below)
            if (db + 1 < 16) {
                const float* sp = emb + (size_t)(code0 + cc) * DDIM + (db + 1) * 16 + hh * 8;
                float4 a = *(const float4*)sp;
                float4 b = *(const float4*)(sp + 4);
                float* dp = &ctb[(db + 1) & 1][cc * STR + hh * 8];
                *(float4*)dp = a;
                *(float4*)(dp + 4) = b;
            }
            const float* cb = &ctb[db & 1][lane * STR];
            const float* zb = z_e + row0 * DDIM + db * 16;  // wave-uniform base
#pragma unroll
            for (int j4 = 0; j4 < 4; ++j4) {
                float4 zv[8];
#pragma unroll
                for (int r = 0; r < 8; ++r)
                    zv[r] = *(const float4*)(zb + r * DDIM + j4 * 4);  // uniform addr -> scalar/broadcast
#pragma unroll
                for (int m = 0; m < 4; ++m) {
                    float4 cv = *(const float4*)(cb + m * 64 * STR + j4 * 4);
#pragma unroll
                    for (int r = 0; r < 8; ++r) {
                        acc[r][m] = __builtin_fmaf(zv[r].x, cv.x, acc[r][m]);
                        acc[r][m] = __builtin_fmaf(zv[r].y, cv.y, acc[r][m]);
                        acc[r][m] = __builtin_fmaf(zv[r].z, cv.z, acc[r][m]);
                        acc[r][m] = __builtin_fmaf(zv[r].w, cv.w, acc[r][m]);
                    }
                }
            }
        }

        // ---- finalize this chunk's distances, lexicographic running min ----
#pragma unroll
        for (int m = 0; m < 4; ++m) {
            const int kk = code0 + m * 64 + lane;
            const float cno = cn_g[kk];
#pragma unroll
            for (int r = 0; r < 8; ++r) {
                float t1 = znb[r] + cno;              // fl(z_norm + c_norm)
                float dv = t1 - 2.0f * acc[r][m];     // fl(t1 - 2*dot); 2*acc exact
                if (dv < mv[r] || (dv == mv[r] && kk < mk[r])) {
                    mv[r] = dv;
                    mk[r] = kk;
                }
            }
        }
    }

    // ---- cross-lane lex-argmin per row (64-lane xor butterfly) ----
#pragma unroll
    for (int r = 0; r < 8; ++r) {
        float bv = mv[r];
        int bk = mk[r];
#pragma unroll
        for (int off = 1; off < 64; off <<= 1) {
            float ov = __shfl_xor(bv, off);
            int ok = __shfl_xor(bk, off);
            if (ov < bv || (ov == bv && ok < bk)) {
                bv = ov;
                bk = ok;
            }
        }
        mv[r] = bv;
        mk[r] = bk;  // all lanes converge to the row's winner
    }
    if (lane == 0) {
#pragma unroll
        for (int r = 0; r < 8; ++r) out_idx[row0 + r] = (float)mk[r];
    }

    // ---- epilogue: z_q_st = fl(z + fl(zq - z)); loss partial ----
    double lsum = 0.0;
#pragma unroll
    for (int r = 0; r < 8; ++r) {
        const float4 a = *(const float4*)(emb + (size_t)mk[r] * DDIM + lane * 4);
        const float4 b = *(const float4*)(z_e + (row0 + r) * DDIM + lane * 4);
        float s0 = a.x - b.x, s1 = a.y - b.y, s2 = a.z - b.z, s3 = a.w - b.w;
        float4 o;
        o.x = b.x + s0;
        o.y = b.y + s1;
        o.z = b.z + s2;
        o.w = b.w + s3;
        *(float4*)(out_zq + (row0 + r) * DDIM + lane * 4) = o;
        lsum += (double)(s0 * s0) + (double)(s1 * s1) + (double)(s2 * s2) + (double)(s3 * s3);
    }
#pragma unroll
    for (int off = 32; off > 0; off >>= 1) lsum += __shfl_down(lsum, off);
    if (lane == 0) wsum[wid] = lsum;
    __syncthreads();
    if (tid == 0) {
        double t = 0.0;
#pragma unroll
        for (int w = 0; w < 8; ++w) t += wsum[w];
        ws_part[bid] = t;
    }
}

__global__ void loss_k(const double* __restrict__ part, float* __restrict__ out_loss) {
    __shared__ double wsum[8];
    int tid = threadIdx.x;
    double s = 0.0;
    for (int i = tid; i < NBLK; i += 512) s += part[i];
#pragma unroll
    for (int off = 32; off > 0; off >>= 1) s += __shfl_down(s, off);
    if ((tid & 63) == 0) wsum[tid >> 6] = s;
    __syncthreads();
    if (tid == 0) {
        double t = 0.0;
#pragma unroll
        for (int w = 0; w < 8; ++w) t += wsum[w];
        out_loss[0] = (float)(COMMIT * (t / ((double)NROWS * (double)DDIM)));
    }
}

extern "C" void kernel_launch(void* const* d_in, const int* in_sizes, int n_in,
                              void* d_out, int out_size, void* d_ws, size_t ws_size,
                              hipStream_t stream) {
    const float* z_e = (const float*)d_in[0];
    const float* emb = (const float*)d_in[1];
    float* out = (float*)d_out;
    float* out_zq = out;
    float* out_idx = out + (size_t)NROWS * DDIM;
    float* out_loss = out_idx + NROWS;

    double* part = (double*)d_ws;                                 // 2048 doubles
    float* cn_g = (float*)((char*)d_ws + NBLK * sizeof(double));  // 1024 floats

    cnorm_k<<<4, 256, 0, stream>>>(emb, cn_g);
    vq_main<<<NBLK, 512, 0, stream>>>(z_e, emb, cn_g, out_zq, out_idx, part);
    loss_k<<<1, 512, 0, stream>>>(part, out_loss);
}

// Round 3
// 1358.706 us; speedup vs baseline: 2.0569x; 2.0569x over previous
//
#include <hip/hip_runtime.h>

#define NROWS 131072
#define KCODES 1024
#define DDIM 256
#define BN 64
#define NBLK (NROWS / BN)   // 2048
#define CHUNK 512           // codes per chunk (2 chunks)
#define STR 20              // LDS row stride (floats): 16 data + 4 pad; 20*4B spreads 8 groups over all 32 banks
#define COMMIT 0.25

// Prevent -ffp-contract=fast from fusing x*x into the following add
// (numpy rounds the product array first, then pairwise-sums).
__device__ __forceinline__ float opq(float x) {
    asm volatile("" : "+v"(x));
    return x;
}

// numpy pairwise half-sum of squares over 128 contiguous elements:
// 8 accumulators r[j] = x[j]+x[j+8]+... (16 terms in order),
// combined as ((r0+r1)+(r2+r3))+((r4+r5)+(r6+r7)).
__device__ __forceinline__ float half128_sq(const float* __restrict__ x) {
    float r[8];
#pragma unroll
    for (int j = 0; j < 8; ++j) {
        float e = x[j];
        float p = e * e;
        p = opq(p);
        r[j] = p;
    }
#pragma unroll
    for (int i = 1; i < 16; ++i) {
#pragma unroll
        for (int j = 0; j < 8; ++j) {
            float e = x[i * 8 + j];
            float p = e * e;
            p = opq(p);
            r[j] += p;
        }
    }
    return ((r[0] + r[1]) + (r[2] + r[3])) + ((r[4] + r[5]) + (r[6] + r[7]));
}

__global__ void cnorm_k(const float* __restrict__ emb, float* __restrict__ cn) {
    int code = blockIdx.x * blockDim.x + threadIdx.x;
    if (code >= KCODES) return;
    const float* x = emb + (size_t)code * DDIM;
    cn[code] = half128_sq(x) + half128_sq(x + 128);
}

__global__ __launch_bounds__(512, 2) void vq_main(
    const float* __restrict__ z_e, const float* __restrict__ emb,
    const float* __restrict__ cn_g, float* __restrict__ out_zq,
    float* __restrict__ out_idx, double* __restrict__ ws_part) {
    __shared__ float c_s[2][CHUNK * STR];  // 81920 B
    __shared__ float z_s[2][BN * STR];     // 10240 B
    __shared__ float cn_l[KCODES];         // 4096 B
    __shared__ float znh[BN][2];
    __shared__ float zn_l[BN];
    __shared__ float red_v[8][BN];
    __shared__ int red_k[8][BN];
    __shared__ int winner[BN];
    __shared__ double wsum[8];

    const int tid = threadIdx.x;
    const int lane = tid & 63;
    const int wv = __builtin_amdgcn_readfirstlane(tid >> 6);  // wave id 0..7 (code panel)
    const int r8 = lane >> 3;  // row group 0..7
    const int c8 = lane & 7;   // code group 0..7
    const int bid = blockIdx.x;
    const size_t row0 = (size_t)bid * BN;

    // ---- c_norm table -> LDS; z_norm halves (np pairwise order) ----
    for (int i = tid; i < KCODES; i += 512) cn_l[i] = cn_g[i];
    if (tid < 128) {
        int row = tid >> 1, h = tid & 1;
        znh[row][h] = half128_sq(z_e + (row0 + row) * DDIM + h * 128);
    }
    __syncthreads();
    if (tid < BN) zn_l[tid] = znh[tid][0] + znh[tid][1];
    // (visibility of zn_l to all waves is guaranteed by the stage-loop barriers below)

    float mv[8];
    int mk[8];
#pragma unroll
    for (int i = 0; i < 8; ++i) {
        mv[i] = __builtin_inff();
        mk[i] = 0;
    }

    for (int ch = 0; ch < 2; ++ch) {
        const int code0 = ch * CHUNK;
        float acc[8][8];
#pragma unroll
        for (int i = 0; i < 8; ++i)
#pragma unroll
            for (int j = 0; j < 8; ++j) acc[i][j] = 0.0f;

        // prologue: stage d-slab 0 into buffer 0
        {
#pragma unroll
            for (int q = 0; q < 4; ++q) {
                int g = q * 512 + tid;
                int code = g >> 2, off = (g & 3) * 4;
                float4 v = *(const float4*)(emb + (size_t)(code0 + code) * DDIM + off);
                *(float4*)&c_s[0][code * STR + off] = v;
            }
            if (tid < 256) {
                int row = tid >> 2, off = (tid & 3) * 4;
                float4 v = *(const float4*)(z_e + (row0 + row) * DDIM + off);
                *(float4*)&z_s[0][row * STR + off] = v;
            }
        }

        for (int st = 0; st < 16; ++st) {
            __syncthreads();
            if (st + 1 < 16) {  // prefetch next 16-d slab into the other buffer
                const int nb = (st + 1) & 1, d0 = (st + 1) * 16;
#pragma unroll
                for (int q = 0; q < 4; ++q) {
                    int g = q * 512 + tid;
                    int code = g >> 2, off = (g & 3) * 4;
                    float4 v = *(const float4*)(emb + (size_t)(code0 + code) * DDIM + d0 + off);
                    *(float4*)&c_s[nb][code * STR + off] = v;
                }
                if (tid < 256) {
                    int row = tid >> 2, off = (tid & 3) * 4;
                    float4 v = *(const float4*)(z_e + (row0 + row) * DDIM + d0 + off);
                    *(float4*)&z_s[nb][row * STR + off] = v;
                }
            }
            const int cb = st & 1;
            const float* cbase = &c_s[cb][(wv * 64 + c8) * STR];
            const float* zbase = &z_s[cb][r8 * STR];
#pragma unroll
            for (int l4 = 0; l4 < 4; ++l4) {
                float4 zv[8], cv[8];
#pragma unroll
                for (int i = 0; i < 8; ++i)
                    zv[i] = *(const float4*)(zbase + i * 8 * STR + l4 * 4);  // 8 distinct addrs, broadcast x8
#pragma unroll
                for (int j = 0; j < 8; ++j)
                    cv[j] = *(const float4*)(cbase + j * 8 * STR + l4 * 4);  // 8 distinct addrs, broadcast x8
#pragma unroll
                for (int i = 0; i < 8; ++i)
#pragma unroll
                    for (int j = 0; j < 8; ++j) {  // per-acc d order: x,y,z,w ascending
                        acc[i][j] = __builtin_fmaf(zv[i].x, cv[j].x, acc[i][j]);
                        acc[i][j] = __builtin_fmaf(zv[i].y, cv[j].y, acc[i][j]);
                        acc[i][j] = __builtin_fmaf(zv[i].z, cv[j].z, acc[i][j]);
                        acc[i][j] = __builtin_fmaf(zv[i].w, cv[j].w, acc[i][j]);
                    }
            }
        }

        // ---- finalize this chunk, lexicographic running min ----
        float znr[8];
#pragma unroll
        for (int i = 0; i < 8; ++i) znr[i] = zn_l[r8 + i * 8];
#pragma unroll
        for (int j = 0; j < 8; ++j) {
            const int kk = code0 + wv * 64 + j * 8 + c8;
            const float cno = cn_l[kk];
#pragma unroll
            for (int i = 0; i < 8; ++i) {
                float t1 = znr[i] + cno;           // fl(z_norm + c_norm)
                float dv = t1 - 2.0f * acc[i][j];  // fl(t1 - 2*dot); 2*acc exact
                if (dv < mv[i] || (dv == mv[i] && kk < mk[i])) {
                    mv[i] = dv;
                    mk[i] = kk;
                }
            }
        }
    }

    // ---- argmin reduce: 8 code-group lanes (consecutive, aligned) per row ----
#pragma unroll
    for (int i = 0; i < 8; ++i) {
        float bv = mv[i];
        int bk = mk[i];
#pragma unroll
        for (int off = 1; off < 8; off <<= 1) {
            float ov = __shfl_xor(bv, off);
            int ok = __shfl_xor(bk, off);
            if (ov < bv || (ov == bv && ok < bk)) {
                bv = ov;
                bk = ok;
            }
        }
        if (c8 == 0) {
            red_v[wv][r8 + i * 8] = bv;
            red_k[wv][r8 + i * 8] = bk;
        }
    }
    __syncthreads();
    if (tid < BN) {  // cross-wave (disjoint ascending code panels): lex scan
        float bv = red_v[0][tid];
        int bk = red_k[0][tid];
#pragma unroll
        for (int w = 1; w < 8; ++w) {
            float v = red_v[w][tid];
            int k = red_k[w][tid];
            if (v < bv || (v == bv && k < bk)) {
                bv = v;
                bk = k;
            }
        }
        winner[tid] = bk;
        out_idx[row0 + tid] = (float)bk;
    }
    __syncthreads();

    // ---- epilogue: z_q_st = fl(z + fl(zq - z)); loss partial ----
    double lsum = 0.0;
    {
        int row = tid >> 3;
        int seg = (tid & 7) * 32;
        int kk = winner[row];
        const float* zq = emb + (size_t)kk * DDIM + seg;
        const float* zz = z_e + (row0 + row) * DDIM + seg;
        float4* dst = (float4*)(out_zq + (row0 + row) * DDIM + seg);
#pragma unroll
        for (int q = 0; q < 8; ++q) {
            float4 a = *(const float4*)(zq + q * 4);
            float4 b = *(const float4*)(zz + q * 4);
            float s0 = a.x - b.x, s1 = a.y - b.y, s2 = a.z - b.z, s3 = a.w - b.w;
            float4 o;
            o.x = b.x + s0;
            o.y = b.y + s1;
            o.z = b.z + s2;
            o.w = b.w + s3;
            dst[q] = o;
            lsum += (double)(s0 * s0) + (double)(s1 * s1) + (double)(s2 * s2) + (double)(s3 * s3);
        }
    }
#pragma unroll
    for (int off = 32; off > 0; off >>= 1) lsum += __shfl_down(lsum, off);
    if (lane == 0) wsum[wv] = lsum;
    __syncthreads();
    if (tid == 0) {
        double t = 0.0;
#pragma unroll
        for (int w = 0; w < 8; ++w) t += wsum[w];
        ws_part[bid] = t;
    }
}

__global__ void loss_k(const double* __restrict__ part, float* __restrict__ out_loss) {
    __shared__ double wsum[8];
    int tid = threadIdx.x;
    double s = 0.0;
    for (int i = tid; i < NBLK; i += 512) s += part[i];
#pragma unroll
    for (int off = 32; off > 0; off >>= 1) s += __shfl_down(s, off);
    if ((tid & 63) == 0) wsum[tid >> 6] = s;
    __syncthreads();
    if (tid == 0) {
        double t = 0.0;
#pragma unroll
        for (int w = 0; w < 8; ++w) t += wsum[w];
        out_loss[0] = (float)(COMMIT * (t / ((double)NROWS * (double)DDIM)));
    }
}

extern "C" void kernel_launch(void* const* d_in, const int* in_sizes, int n_in,
                              void* d_out, int out_size, void* d_ws, size_t ws_size,
                              hipStream_t stream) {
    const float* z_e = (const float*)d_in[0];
    const float* emb = (const float*)d_in[1];
    float* out = (float*)d_out;
    float* out_zq = out;
    float* out_idx = out + (size_t)NROWS * DDIM;
    float* out_loss = out_idx + NROWS;

    double* part = (double*)d_ws;                                 // 2048 doubles
    float* cn_g = (float*)((char*)d_ws + NBLK * sizeof(double));  // 1024 floats

    cnorm_k<<<4, 256, 0, stream>>>(emb, cn_g);
    vq_main<<<NBLK, 512, 0, stream>>>(z_e, emb, cn_g, out_zq, out_idx, part);
    loss_k<<<1, 512, 0, stream>>>(part, out_loss);
}